// Round 6
// baseline (325.120 us; speedup 1.0000x reference)
//
#include <hip/hip_runtime.h>

// Problem constants (fixed by reference)
#define T_SEQ 1024
#define BATCH 8
#define DMODEL 1024
#define NHEAD 16
#define HDIM 64
#define M_ROWS (T_SEQ * BATCH)   // 8192
// attention scale 0.125 with log2(e) folded in (exp -> exp2)
#define QSCALE (0.125f * 1.44269504088896f)

#define N4BIG   (M_ROWS * DMODEL / 4)    // 2097152 = 1<<21 float4-chunks per big tensor
#define N4SMALL (DMODEL * DMODEL / 4)    // 262144  = 1<<18 per weight tensor

typedef unsigned short ushort_t;
typedef __attribute__((ext_vector_type(8))) short short8;   // 8 bf16 = 4 VGPRs (MFMA A/B frag)
typedef __attribute__((ext_vector_type(4))) float f32x4;    // MFMA C/D frag

// async global->LDS, 16B per lane; LDS dest = wave-uniform base + lane*16
#define G2L16(g, l) __builtin_amdgcn_global_load_lds(                      \
    (const __attribute__((address_space(1))) void*)(g),                    \
    (__attribute__((address_space(3))) void*)(l), 16, 0, 0)

#define SBAR()   __builtin_amdgcn_s_barrier()
#define LGKM0()  asm volatile("s_waitcnt lgkmcnt(0)" ::: "memory")
#define SCHEDB() __builtin_amdgcn_sched_barrier(0)

// f32 -> bf16 round-to-nearest-even (finite inputs only)
static __device__ __forceinline__ ushort_t f2bf(float f) {
    unsigned int u = __builtin_bit_cast(unsigned int, f);
    u += 0x7FFFu + ((u >> 16) & 1u);
    return (ushort_t)(u >> 16);
}

// pack two f32 -> bf16x2 (lo in [15:0], hi in [31:16]), RNE
#if __has_builtin(__builtin_amdgcn_cvt_pk_bf16_f32)
typedef __attribute__((ext_vector_type(2))) __bf16 bf16x2_t;
static __device__ __forceinline__ unsigned pk2(float lo, float hi) {
    bf16x2_t r = __builtin_amdgcn_cvt_pk_bf16_f32(lo, hi);
    return __builtin_bit_cast(unsigned, r);
}
#else
static __device__ __forceinline__ unsigned pk2(float lo, float hi) {
    return (unsigned)f2bf(lo) | ((unsigned)f2bf(hi) << 16);
}
#endif

// raw v_exp_f32 (2^x)
#if __has_builtin(__builtin_amdgcn_exp2f)
#define EXP2F(x) __builtin_amdgcn_exp2f(x)
#else
#define EXP2F(x) exp2f(x)
#endif

// ---------------------------------------------------------------------------
// Exact-size 1D fused cast: 3 big tensors (q,k,v) then 4 weights.
// Ranges are pow-2 so the split is shift/mask; whole blocks stay uniform.
// grid = (3*N4BIG + 4*N4SMALL)/256 = 28672 blocks (no immediate-exit blocks).
// ---------------------------------------------------------------------------
__global__ __launch_bounds__(256) void cast_all_1d(
    const float4* __restrict__ q, const float4* __restrict__ k,
    const float4* __restrict__ v, const float4* __restrict__ wq,
    const float4* __restrict__ wk, const float4* __restrict__ wv,
    const float4* __restrict__ wo,
    uint2* __restrict__ dq, uint2* __restrict__ dk, uint2* __restrict__ dv,
    uint2* __restrict__ dwq, uint2* __restrict__ dwk, uint2* __restrict__ dwv,
    uint2* __restrict__ dwo)
{
    const int i = blockIdx.x * 256 + threadIdx.x;
    const float4* s; uint2* d; int off;
    if (i < 3 * N4BIG) {
        const int t = i >> 21;                 // 0..2
        off = i & (N4BIG - 1);
        s = (t == 0) ? q : (t == 1) ? k : v;
        d = (t == 0) ? dq : (t == 1) ? dk : dv;
    } else {
        const int j = i - 3 * N4BIG;
        const int t = j >> 18;                 // 0..3
        off = j & (N4SMALL - 1);
        s = (t == 0) ? wq : (t == 1) ? wk : (t == 2) ? wv : wo;
        d = (t == 0) ? dwq : (t == 1) ? dwk : (t == 2) ? dwv : dwo;
    }
    float4 val = s[off];
    uint2 o; o.x = pk2(val.x, val.y); o.y = pk2(val.z, val.w);
    d[off] = o;
}

// ---------------------------------------------------------------------------
// Proven 128x128 4-wave MFMA GEMM + chunked XCD swizzle.
// Swizzle: HW dispatches linear id L to XCD L%8; remap so XCD k processes
// contiguous tile-ids t = k*(nwg/8).. -> all 8 bn-blocks sharing one A-panel
// (same bmg) run on ONE XCD's L2 (bn-fastest in t). Round-1 counters showed
// FETCH 200.8 MB vs 54 MB minimum (A panel fetched by 8 XCDs); this swizzle
// targets that over-fetch. Requires nwg%8==0 (1536, 512: both OK) and
// gridDim.x==8 (N=1024).
// Multi-segment: sel = bmg>>6 picks weight/bias (QKV fusion).
// ---------------------------------------------------------------------------
template<bool OUT_BF16>
__global__ __launch_bounds__(256) void gemm_bt_mfma(
    const ushort_t* __restrict__ A, const ushort_t* __restrict__ Wbase,
    const float* __restrict__ bias0, const float* __restrict__ bias1,
    const float* __restrict__ bias2, void* __restrict__ Yv,
    int N, int K, float scale0)
{
    __shared__ ushort_t As[128 * 64];
    __shared__ ushort_t Bs[128 * 64];

    const int tid  = threadIdx.x;
    const int lane = tid & 63;
    const int quad = lane >> 4;
    const int l16  = lane & 15;
    const int w    = tid >> 6;
    const int wm   = w >> 1;
    const int wn   = w & 1;

    // chunked XCD swizzle (bijective: nwg % 8 == 0)
    const int nwg = gridDim.x * gridDim.y;
    const int lin = blockIdx.y * gridDim.x + blockIdx.x;
    const int t   = (lin & 7) * (nwg >> 3) + (lin >> 3);
    const int bn  = t & 7;            // gridDim.x == 8
    const int bmg = t >> 3;

    const int sel = bmg >> 6;                 // 0..2 for QKV, 0 for O-proj
    const ushort_t* Wb = Wbase + (size_t)sel * N * K;
    const float* bias = (sel == 0) ? bias0 : (sel == 1) ? bias1 : bias2;
    const float scale = (sel == 0) ? scale0 : 1.0f;

    const int srow_in = lane >> 3;            // 0..7 within 8-row segment
    const int sch     = lane & 7;             // chunk slot 0..7

    const f32x4 zero4 = {0.f, 0.f, 0.f, 0.f};
    f32x4 acc[4][4];
#pragma unroll
    for (int i = 0; i < 4; i++)
#pragma unroll
        for (int j = 0; j < 4; j++) acc[i][j] = zero4;

    for (int k0 = 0; k0 < K; k0 += 64) {
        __syncthreads();   // previous iter done reading LDS
#pragma unroll
        for (int u = 0; u < 4; u++) {
            int seg = w * 4 + u;              // 0..15, 8 rows each
            int row = seg * 8 + srow_in;      // 0..127
            int chs = sch ^ (row & 7);
            G2L16(&A [(size_t)(bmg * 128 + row) * K + k0 + chs * 8],
                  (char*)As + seg * 1024);
            G2L16(&Wb[(size_t)(bn  * 128 + row) * K + k0 + chs * 8],
                  (char*)Bs + seg * 1024);
        }
        __syncthreads();   // DMA drained

#pragma unroll
        for (int ks = 0; ks < 2; ks++) {
            short8 af[4], bfr[4];
#pragma unroll
            for (int i = 0; i < 4; i++) {
                int row = wm * 64 + i * 16 + l16;
                af[i] = *(const short8*)&As[row * 64 + (((ks * 4 + quad) ^ (row & 7)) * 8)];
            }
#pragma unroll
            for (int j = 0; j < 4; j++) {
                int row = wn * 64 + j * 16 + l16;
                bfr[j] = *(const short8*)&Bs[row * 64 + (((ks * 4 + quad) ^ (row & 7)) * 8)];
            }
#pragma unroll
            for (int i = 0; i < 4; i++)
#pragma unroll
                for (int j = 0; j < 4; j++)
                    acc[i][j] = __builtin_amdgcn_mfma_f32_16x16x32_bf16(
                        af[i], bfr[j], acc[i][j], 0, 0, 0);
        }
    }

    float bj[4];
#pragma unroll
    for (int j = 0; j < 4; j++) bj[j] = bias[bn * 128 + wn * 64 + j * 16 + l16];
#pragma unroll
    for (int i = 0; i < 4; i++) {
#pragma unroll
        for (int r = 0; r < 4; r++) {
            size_t row = (size_t)(bmg * 128 + wm * 64 + i * 16 + quad * 4 + r);
#pragma unroll
            for (int j = 0; j < 4; j++) {
                int col = bn * 128 + wn * 64 + j * 16 + l16;
                float v = (acc[i][j][r] + bj[j]) * scale;
                if (OUT_BF16) ((ushort_t*)Yv)[row * N + col] = f2bf(v);
                else          ((float*)   Yv)[row * N + col] = v;
            }
        }
    }
}

// ---------------------------------------------------------------------------
// Vp (T,B,H,HD) bf16 -> Vt (B,H,HD,T) bf16  (64x64 tiles through LDS)
// ---------------------------------------------------------------------------
__global__ __launch_bounds__(256) void transpose_v(
    const ushort_t* __restrict__ Vp, ushort_t* __restrict__ Vt)
{
    __shared__ ushort_t Ts[64][72];
    const int tid = threadIdx.x;
    const int t0 = blockIdx.x * 64;
    const int bh = blockIdx.y;
    const int b = bh >> 4, h = bh & 15;

#pragma unroll
    for (int u = 0; u < 2; u++) {
        int e = u * 256 + tid;          // 512 chunks of 8 bf16
        int row = e >> 3, ch = (e & 7) * 8;
        uint4 v = *(const uint4*)&Vp[((size_t)(t0 + row) * BATCH + b) * DMODEL + h * 64 + ch];
        *(uint4*)&Ts[row][ch] = v;
    }
    __syncthreads();
#pragma unroll
    for (int u = 0; u < 2; u++) {
        int e = u * 256 + tid;
        int d = e >> 3, tc = (e & 7) * 8;
        uint4 o;
        o.x = (unsigned)Ts[tc + 0][d] | ((unsigned)Ts[tc + 1][d] << 16);
        o.y = (unsigned)Ts[tc + 2][d] | ((unsigned)Ts[tc + 3][d] << 16);
        o.z = (unsigned)Ts[tc + 4][d] | ((unsigned)Ts[tc + 5][d] << 16);
        o.w = (unsigned)Ts[tc + 6][d] | ((unsigned)Ts[tc + 7][d] << 16);
        *(uint4*)&Vt[((size_t)(bh * 64 + d)) * T_SEQ + t0 + tc] = o;
    }
}

// ---------------------------------------------------------------------------
// MFMA flash attention, S^T formulation. Double-buffered K/V staging with
// own-drain vmcnt BEFORE the barrier (loads are a full iteration old at the
// wait -> latency hidden); 1 barrier per s-tile. (Round-3 proven, ~-15 µs.)
// ---------------------------------------------------------------------------
__global__ __launch_bounds__(256) void attn_mfma(
    const ushort_t* __restrict__ Qp, const ushort_t* __restrict__ Kp,
    const ushort_t* __restrict__ VtG, ushort_t* __restrict__ Ao)
{
    __shared__ ushort_t Ks[2][64 * 64];  // [s][hd], swizzled, double-buffered
    __shared__ ushort_t Vs[2][64 * 64];  // [hd][s], same structure
    __shared__ ushort_t Pl[4][32][72];   // per-wave P / O-bounce, pitch 72

    const int tid  = threadIdx.x;
    const int lane = tid & 63;
    const int w    = tid >> 6;
    const int quad = lane >> 4;
    const int l16  = lane & 15;
    const int bid  = blockIdx.x;
    const int qb   = bid >> 7;          // 0..7
    const int bh   = bid & 127;
    const int b    = bh >> 4, h = bh & 15;
    const int hoff = h * 64;
    const int q0   = qb * 128 + w * 32;  // this wave's 32 Q rows

    const int srow_in = lane >> 3;       // 0..7 within 8-row segment
    const int sch     = lane & 7;

    // Q fragments (B-operand; same layout as A), in registers all kernel
    short8 qf[2][2];
#pragma unroll
    for (int rt = 0; rt < 2; rt++)
#pragma unroll
        for (int ks = 0; ks < 2; ks++)
            qf[rt][ks] = *(const short8*)&Qp[((size_t)(q0 + rt * 16 + l16) * BATCH + b) * DMODEL
                                             + hoff + ks * 32 + quad * 8];

    short8 ones;
#pragma unroll
    for (int i = 0; i < 8; i++) ones[i] = (short)0x3F80;   // bf16 1.0

    const f32x4 zero4 = {0.f, 0.f, 0.f, 0.f};
    f32x4 oacc[2][4], lacc[2];
#pragma unroll
    for (int rt = 0; rt < 2; rt++) {
        lacc[rt] = zero4;
#pragma unroll
        for (int c = 0; c < 4; c++) oacc[rt][c] = zero4;
    }

#define STAGE_KV(s0_, buf)                                                       \
    do {                                                                         \
        _Pragma("unroll")                                                        \
        for (int u = 0; u < 2; u++) {                                            \
            int seg = w * 2 + u;                                                 \
            int row = seg * 8 + srow_in;                                         \
            int chs = sch ^ (row & 7);                                           \
            G2L16(&Kp[((size_t)((s0_) + row) * BATCH + b) * DMODEL + hoff + chs * 8], \
                  (char*)&Ks[buf][0] + seg * 1024);                              \
            G2L16(&VtG[((size_t)(bh * 64 + row)) * T_SEQ + (s0_) + chs * 8],     \
                  (char*)&Vs[buf][0] + seg * 1024);                              \
        }                                                                        \
    } while (0)

    STAGE_KV(0, 0);

    for (int it = 0; it < 16; ++it) {
        const int cur = it & 1;

        // own-drain before barrier: tile-it loads (issued >=1 full compute
        // phase ago) landed; after join, all waves' segments are valid.
        asm volatile("s_waitcnt vmcnt(0)" ::: "memory");
        SBAR();
        SCHEDB();
        if (it + 1 < 16) STAGE_KV((it + 1) * 64, cur ^ 1);

        // ---- S^T = K . Q^T : per c-tile D[m=s in c*16..][n=q] ----
        f32x4 sacc[2][4];
#pragma unroll
        for (int rt = 0; rt < 2; rt++)
#pragma unroll
            for (int c = 0; c < 4; c++) sacc[rt][c] = zero4;
        __builtin_amdgcn_s_setprio(1);
#pragma unroll
        for (int c = 0; c < 4; c++) {
            int row = c * 16 + l16;
#pragma unroll
            for (int ks = 0; ks < 2; ks++) {
                short8 kf = *(const short8*)&Ks[cur][row * 64 + (((ks * 4 + quad) ^ (row & 7)) * 8)];
#pragma unroll
                for (int rt = 0; rt < 2; rt++)
                    sacc[rt][c] = __builtin_amdgcn_mfma_f32_16x16x32_bf16(
                        kf, qf[rt][ks], sacc[rt][c], 0, 0, 0);
            }
        }
        __builtin_amdgcn_s_setprio(0);

        // ---- P = exp2(S): packed b64 writes, already B-fragment layout ----
#pragma unroll
        for (int rt = 0; rt < 2; rt++)
#pragma unroll
            for (int c = 0; c < 4; c++) {
                uint2 pv;
                pv.x = pk2(EXP2F(sacc[rt][c][0]), EXP2F(sacc[rt][c][1]));
                pv.y = pk2(EXP2F(sacc[rt][c][2]), EXP2F(sacc[rt][c][3]));
                *(uint2*)&Pl[w][rt * 16 + l16][c * 16 + quad * 4] = pv;
            }

        short8 pf[2][2];
#pragma unroll
        for (int rt = 0; rt < 2; rt++)
#pragma unroll
            for (int ks = 0; ks < 2; ks++)
                pf[rt][ks] = *(const short8*)&Pl[w][rt * 16 + l16][ks * 32 + quad * 8];

        // ---- denominator: lacc[n=q] += sum_s P[q][s] ----
#pragma unroll
        for (int rt = 0; rt < 2; rt++)
#pragma unroll
            for (int ks = 0; ks < 2; ks++)
                lacc[rt] = __builtin_amdgcn_mfma_f32_16x16x32_bf16(
                    ones, pf[rt][ks], lacc[rt], 0, 0, 0);

        // ---- O^T += V^T . P^T : D[m=d][n=q] ----
        __builtin_amdgcn_s_setprio(1);
#pragma unroll
        for (int dt = 0; dt < 4; dt++) {
            int row = dt * 16 + l16;
#pragma unroll
            for (int ks = 0; ks < 2; ks++) {
                short8 vf = *(const short8*)&Vs[cur][row * 64 + (((ks * 4 + quad) ^ (row & 7)) * 8)];
#pragma unroll
                for (int rt = 0; rt < 2; rt++)
                    oacc[rt][dt] = __builtin_amdgcn_mfma_f32_16x16x32_bf16(
                        vf, pf[rt][ks], oacc[rt][dt], 0, 0, 0);
            }
        }
        __builtin_amdgcn_s_setprio(0);

        // retire this tile's ds_reads before next iteration's barrier
        LGKM0();
    }
#undef STAGE_KV

    // ---- normalize (per-lane, no shuffles), bounce through Pl, store ----
#pragma unroll
    for (int rt = 0; rt < 2; rt++) {
        float inv = 1.f / lacc[rt][0];   // all 4 regs identical (A=ones)
#pragma unroll
        for (int dt = 0; dt < 4; dt++) {
            uint2 ov;
            ov.x = pk2(oacc[rt][dt][0] * inv, oacc[rt][dt][1] * inv);
            ov.y = pk2(oacc[rt][dt][2] * inv, oacc[rt][dt][3] * inv);
            *(uint2*)&Pl[w][rt * 16 + l16][dt * 16 + quad * 4] = ov;
        }
    }
    // coalesced 16B stores: 8 lanes cover one 128B row
#pragma unroll
    for (int it = 0; it < 4; it++) {
        int row = it * 8 + (lane >> 3);
        int ch  = lane & 7;
        uint4 val = *(const uint4*)&Pl[w][row][ch * 8];
        *(uint4*)&Ao[((size_t)(q0 + row) * BATCH + b) * DMODEL + hoff + ch * 8] = val;
    }
}

// ---------------------------------------------------------------------------
extern "C" void kernel_launch(void* const* d_in, const int* in_sizes, int n_in,
                              void* d_out, int out_size, void* d_ws, size_t ws_size,
                              hipStream_t stream)
{
    const float* q  = (const float*)d_in[0];
    const float* k  = (const float*)d_in[1];
    const float* v  = (const float*)d_in[2];
    const float* Wq = (const float*)d_in[3];
    const float* bq = (const float*)d_in[4];
    const float* Wk = (const float*)d_in[5];
    const float* bk = (const float*)d_in[6];
    const float* Wv = (const float*)d_in[7];
    const float* bv = (const float*)d_in[8];
    const float* Wo = (const float*)d_in[9];
    const float* bo = (const float*)d_in[10];

    ushort_t* ws = (ushort_t*)d_ws;
    const size_t E = (size_t)M_ROWS * DMODEL;    // 8388608
    const size_t EW = (size_t)DMODEL * DMODEL;   // 1048576
    ushort_t* qb  = ws;            // input q bf16; reused as Vt
    ushort_t* kb  = ws + E;        // input k bf16; reused as Aob
    ushort_t* vb  = ws + 2 * E;
    ushort_t* Qp  = ws + 3 * E;
    ushort_t* Kp  = ws + 4 * E;
    ushort_t* Vp  = ws + 5 * E;
    ushort_t* Wqb = ws + 6 * E;
    ushort_t* Wkb = Wqb + EW;
    ushort_t* Wvb = Wkb + EW;
    ushort_t* Wob = Wvb + EW;
    ushort_t* Vt  = qb;
    ushort_t* Aob = kb;

    const int ncast = (3 * N4BIG + 4 * N4SMALL) / 256;   // 28672 blocks
    cast_all_1d<<<dim3(ncast), 256, 0, stream>>>(
        (const float4*)q, (const float4*)k, (const float4*)v,
        (const float4*)Wq, (const float4*)Wk, (const float4*)Wv, (const float4*)Wo,
        (uint2*)qb, (uint2*)kb, (uint2*)vb,
        (uint2*)Wqb, (uint2*)Wkb, (uint2*)Wvb, (uint2*)Wob);

    // fused QKV projection: 128-tile kernel + XCD swizzle, M = 3*8192.
    gemm_bt_mfma<true><<<dim3(DMODEL / 128, 3 * M_ROWS / 128), 256, 0, stream>>>(
        qb, Wqb, bq, bk, bv, Qp, DMODEL, DMODEL, QSCALE);

    transpose_v<<<dim3(T_SEQ / 64, BATCH * NHEAD), 256, 0, stream>>>(Vp, Vt);

    attn_mfma<<<dim3(8 * 128), 256, 0, stream>>>(Qp, Kp, Vt, Aob);

    // O-proj: 128-tile kernel + XCD swizzle (512 blocks = 2/CU)
    gemm_bt_mfma<false><<<dim3(DMODEL / 128, M_ROWS / 128), 256, 0, stream>>>(
        Aob, Wob, bo, bo, bo, d_out, DMODEL, DMODEL, 1.0f);
}

// Round 7
// 306.456 us; speedup vs baseline: 1.0609x; 1.0609x over previous
//
#include <hip/hip_runtime.h>

// Problem constants (fixed by reference)
#define T_SEQ 1024
#define BATCH 8
#define DMODEL 1024
#define NHEAD 16
#define HDIM 64
#define M_ROWS (T_SEQ * BATCH)   // 8192
// attention scale 0.125 with log2(e) folded in (exp -> exp2)
#define QSCALE (0.125f * 1.44269504088896f)

typedef unsigned short ushort_t;
typedef __attribute__((ext_vector_type(8))) short short8;   // 8 bf16 = 4 VGPRs (MFMA A/B frag)
typedef __attribute__((ext_vector_type(4))) float f32x4;    // MFMA C/D frag

// async global->LDS, 16B per lane; LDS dest = wave-uniform base + lane*16
#define G2L16(g, l) __builtin_amdgcn_global_load_lds(                      \
    (const __attribute__((address_space(1))) void*)(g),                    \
    (__attribute__((address_space(3))) void*)(l), 16, 0, 0)

#define SBAR()   __builtin_amdgcn_s_barrier()
#define LGKM0()  asm volatile("s_waitcnt lgkmcnt(0)" ::: "memory")
#define SCHEDB() __builtin_amdgcn_sched_barrier(0)

// f32 -> bf16 round-to-nearest-even (finite inputs only)
static __device__ __forceinline__ ushort_t f2bf(float f) {
    unsigned int u = __builtin_bit_cast(unsigned int, f);
    u += 0x7FFFu + ((u >> 16) & 1u);
    return (ushort_t)(u >> 16);
}

// pack two f32 -> bf16x2 (lo in [15:0], hi in [31:16]), RNE
#if __has_builtin(__builtin_amdgcn_cvt_pk_bf16_f32)
typedef __attribute__((ext_vector_type(2))) __bf16 bf16x2_t;
static __device__ __forceinline__ unsigned pk2(float lo, float hi) {
    bf16x2_t r = __builtin_amdgcn_cvt_pk_bf16_f32(lo, hi);
    return __builtin_bit_cast(unsigned, r);
}
#else
static __device__ __forceinline__ unsigned pk2(float lo, float hi) {
    return (unsigned)f2bf(lo) | ((unsigned)f2bf(hi) << 16);
}
#endif

// raw v_exp_f32 (2^x)
#if __has_builtin(__builtin_amdgcn_exp2f)
#define EXP2F(x) __builtin_amdgcn_exp2f(x)
#else
#define EXP2F(x) exp2f(x)
#endif

// ---------------------------------------------------------------------------
// Fused f32 -> bf16 cast of all 7 tensors: grid.y selects tensor (uniform
// per block -> scalar pointer selects; proven form from rounds 3/5).
// ---------------------------------------------------------------------------
__global__ __launch_bounds__(256) void cast_all_bf16(
    const float4* __restrict__ s0, const float4* __restrict__ s1,
    const float4* __restrict__ s2, const float4* __restrict__ s3,
    const float4* __restrict__ s4, const float4* __restrict__ s5,
    const float4* __restrict__ s6,
    uint2* __restrict__ d0, uint2* __restrict__ d1, uint2* __restrict__ d2,
    uint2* __restrict__ d3, uint2* __restrict__ d4, uint2* __restrict__ d5,
    uint2* __restrict__ d6, int n4big, int n4small)
{
    const int y = blockIdx.y;
    const int n4 = (y < 3) ? n4big : n4small;
    const int i = blockIdx.x * 256 + threadIdx.x;
    if (i >= n4) return;
    const float4* s; uint2* d;
    switch (y) {
        case 0: s = s0; d = d0; break;
        case 1: s = s1; d = d1; break;
        case 2: s = s2; d = d2; break;
        case 3: s = s3; d = d3; break;
        case 4: s = s4; d = d4; break;
        case 5: s = s5; d = d5; break;
        default: s = s6; d = d6; break;
    }
    float4 v = s[i];
    uint2 o; o.x = pk2(v.x, v.y); o.y = pk2(v.z, v.w);
    d[i] = o;
}

// ---------------------------------------------------------------------------
// Proven 128x128 4-wave MFMA GEMM + chunked XCD swizzle (round-6: FETCH
// 200.8 -> 44 MB verified). NEW this round: __launch_bounds__(256, 4) --
// round-6 counters showed OccupancyPercent 25% (2 blocks/CU) though LDS
// (32 KiB -> 5) and VGPR (84 -> 6) allow more; 4 waves/SIMD hint packs
// 4 blocks/CU so the barrier-drain overlaps across blocks.
// Multi-segment: sel = bmg>>6 picks weight/bias (QKV fusion).
// ---------------------------------------------------------------------------
template<bool OUT_BF16>
__global__ __launch_bounds__(256, 4) void gemm_bt_mfma(
    const ushort_t* __restrict__ A, const ushort_t* __restrict__ Wbase,
    const float* __restrict__ bias0, const float* __restrict__ bias1,
    const float* __restrict__ bias2, void* __restrict__ Yv,
    int N, int K, float scale0)
{
    __shared__ ushort_t As[128 * 64];
    __shared__ ushort_t Bs[128 * 64];

    const int tid  = threadIdx.x;
    const int lane = tid & 63;
    const int quad = lane >> 4;
    const int l16  = lane & 15;
    const int w    = tid >> 6;
    const int wm   = w >> 1;
    const int wn   = w & 1;

    // chunked XCD swizzle (bijective: nwg % 8 == 0)
    const int nwg = gridDim.x * gridDim.y;
    const int lin = blockIdx.y * gridDim.x + blockIdx.x;
    const int t   = (lin & 7) * (nwg >> 3) + (lin >> 3);
    const int bn  = t & 7;            // gridDim.x == 8
    const int bmg = t >> 3;

    const int sel = bmg >> 6;                 // 0..2 for QKV, 0 for O-proj
    const ushort_t* Wb = Wbase + (size_t)sel * N * K;
    const float* bias = (sel == 0) ? bias0 : (sel == 1) ? bias1 : bias2;
    const float scale = (sel == 0) ? scale0 : 1.0f;

    const int srow_in = lane >> 3;            // 0..7 within 8-row segment
    const int sch     = lane & 7;             // chunk slot 0..7

    const f32x4 zero4 = {0.f, 0.f, 0.f, 0.f};
    f32x4 acc[4][4];
#pragma unroll
    for (int i = 0; i < 4; i++)
#pragma unroll
        for (int j = 0; j < 4; j++) acc[i][j] = zero4;

    for (int k0 = 0; k0 < K; k0 += 64) {
        __syncthreads();   // previous iter done reading LDS
#pragma unroll
        for (int u = 0; u < 4; u++) {
            int seg = w * 4 + u;              // 0..15, 8 rows each
            int row = seg * 8 + srow_in;      // 0..127
            int chs = sch ^ (row & 7);
            G2L16(&A [(size_t)(bmg * 128 + row) * K + k0 + chs * 8],
                  (char*)As + seg * 1024);
            G2L16(&Wb[(size_t)(bn  * 128 + row) * K + k0 + chs * 8],
                  (char*)Bs + seg * 1024);
        }
        __syncthreads();   // DMA drained

#pragma unroll
        for (int ks = 0; ks < 2; ks++) {
            short8 af[4], bfr[4];
#pragma unroll
            for (int i = 0; i < 4; i++) {
                int row = wm * 64 + i * 16 + l16;
                af[i] = *(const short8*)&As[row * 64 + (((ks * 4 + quad) ^ (row & 7)) * 8)];
            }
#pragma unroll
            for (int j = 0; j < 4; j++) {
                int row = wn * 64 + j * 16 + l16;
                bfr[j] = *(const short8*)&Bs[row * 64 + (((ks * 4 + quad) ^ (row & 7)) * 8)];
            }
#pragma unroll
            for (int i = 0; i < 4; i++)
#pragma unroll
                for (int j = 0; j < 4; j++)
                    acc[i][j] = __builtin_amdgcn_mfma_f32_16x16x32_bf16(
                        af[i], bfr[j], acc[i][j], 0, 0, 0);
        }
    }

    float bj[4];
#pragma unroll
    for (int j = 0; j < 4; j++) bj[j] = bias[bn * 128 + wn * 64 + j * 16 + l16];
#pragma unroll
    for (int i = 0; i < 4; i++) {
#pragma unroll
        for (int r = 0; r < 4; r++) {
            size_t row = (size_t)(bmg * 128 + wm * 64 + i * 16 + quad * 4 + r);
#pragma unroll
            for (int j = 0; j < 4; j++) {
                int col = bn * 128 + wn * 64 + j * 16 + l16;
                float v = (acc[i][j][r] + bj[j]) * scale;
                if (OUT_BF16) ((ushort_t*)Yv)[row * N + col] = f2bf(v);
                else          ((float*)   Yv)[row * N + col] = v;
            }
        }
    }
}

// ---------------------------------------------------------------------------
// Vp (T,B,H,HD) bf16 -> Vt (B,H,HD,T) bf16  (64x64 tiles through LDS)
// ---------------------------------------------------------------------------
__global__ __launch_bounds__(256) void transpose_v(
    const ushort_t* __restrict__ Vp, ushort_t* __restrict__ Vt)
{
    __shared__ ushort_t Ts[64][72];
    const int tid = threadIdx.x;
    const int t0 = blockIdx.x * 64;
    const int bh = blockIdx.y;
    const int b = bh >> 4, h = bh & 15;

#pragma unroll
    for (int u = 0; u < 2; u++) {
        int e = u * 256 + tid;          // 512 chunks of 8 bf16
        int row = e >> 3, ch = (e & 7) * 8;
        uint4 v = *(const uint4*)&Vp[((size_t)(t0 + row) * BATCH + b) * DMODEL + h * 64 + ch];
        *(uint4*)&Ts[row][ch] = v;
    }
    __syncthreads();
#pragma unroll
    for (int u = 0; u < 2; u++) {
        int e = u * 256 + tid;
        int d = e >> 3, tc = (e & 7) * 8;
        uint4 o;
        o.x = (unsigned)Ts[tc + 0][d] | ((unsigned)Ts[tc + 1][d] << 16);
        o.y = (unsigned)Ts[tc + 2][d] | ((unsigned)Ts[tc + 3][d] << 16);
        o.z = (unsigned)Ts[tc + 4][d] | ((unsigned)Ts[tc + 5][d] << 16);
        o.w = (unsigned)Ts[tc + 6][d] | ((unsigned)Ts[tc + 7][d] << 16);
        *(uint4*)&Vt[((size_t)(bh * 64 + d)) * T_SEQ + t0 + tc] = o;
    }
}

// ---------------------------------------------------------------------------
// MFMA flash attention, S^T formulation. Double-buffered K/V staging with
// own-drain vmcnt BEFORE the barrier; 1 barrier per s-tile.
// __launch_bounds__(256,3): LDS (50 KiB) allows 3 blocks/CU; cap VGPR so
// the compiler doesn't allocate past the 3-block threshold.
// ---------------------------------------------------------------------------
__global__ __launch_bounds__(256, 3) void attn_mfma(
    const ushort_t* __restrict__ Qp, const ushort_t* __restrict__ Kp,
    const ushort_t* __restrict__ VtG, ushort_t* __restrict__ Ao)
{
    __shared__ ushort_t Ks[2][64 * 64];  // [s][hd], swizzled, double-buffered
    __shared__ ushort_t Vs[2][64 * 64];  // [hd][s], same structure
    __shared__ ushort_t Pl[4][32][72];   // per-wave P / O-bounce, pitch 72

    const int tid  = threadIdx.x;
    const int lane = tid & 63;
    const int w    = tid >> 6;
    const int quad = lane >> 4;
    const int l16  = lane & 15;
    const int bid  = blockIdx.x;
    const int qb   = bid >> 7;          // 0..7
    const int bh   = bid & 127;
    const int b    = bh >> 4, h = bh & 15;
    const int hoff = h * 64;
    const int q0   = qb * 128 + w * 32;  // this wave's 32 Q rows

    const int srow_in = lane >> 3;       // 0..7 within 8-row segment
    const int sch     = lane & 7;

    // Q fragments (B-operand; same layout as A), in registers all kernel
    short8 qf[2][2];
#pragma unroll
    for (int rt = 0; rt < 2; rt++)
#pragma unroll
        for (int ks = 0; ks < 2; ks++)
            qf[rt][ks] = *(const short8*)&Qp[((size_t)(q0 + rt * 16 + l16) * BATCH + b) * DMODEL
                                             + hoff + ks * 32 + quad * 8];

    short8 ones;
#pragma unroll
    for (int i = 0; i < 8; i++) ones[i] = (short)0x3F80;   // bf16 1.0

    const f32x4 zero4 = {0.f, 0.f, 0.f, 0.f};
    f32x4 oacc[2][4], lacc[2];
#pragma unroll
    for (int rt = 0; rt < 2; rt++) {
        lacc[rt] = zero4;
#pragma unroll
        for (int c = 0; c < 4; c++) oacc[rt][c] = zero4;
    }

#define STAGE_KV(s0_, buf)                                                       \
    do {                                                                         \
        _Pragma("unroll")                                                        \
        for (int u = 0; u < 2; u++) {                                            \
            int seg = w * 2 + u;                                                 \
            int row = seg * 8 + srow_in;                                         \
            int chs = sch ^ (row & 7);                                           \
            G2L16(&Kp[((size_t)((s0_) + row) * BATCH + b) * DMODEL + hoff + chs * 8], \
                  (char*)&Ks[buf][0] + seg * 1024);                              \
            G2L16(&VtG[((size_t)(bh * 64 + row)) * T_SEQ + (s0_) + chs * 8],     \
                  (char*)&Vs[buf][0] + seg * 1024);                              \
        }                                                                        \
    } while (0)

    STAGE_KV(0, 0);

    for (int it = 0; it < 16; ++it) {
        const int cur = it & 1;

        // own-drain before barrier: tile-it loads (issued >=1 full compute
        // phase ago) landed; after join, all waves' segments are valid.
        asm volatile("s_waitcnt vmcnt(0)" ::: "memory");
        SBAR();
        SCHEDB();
        if (it + 1 < 16) STAGE_KV((it + 1) * 64, cur ^ 1);

        // ---- S^T = K . Q^T : per c-tile D[m=s in c*16..][n=q] ----
        f32x4 sacc[2][4];
#pragma unroll
        for (int rt = 0; rt < 2; rt++)
#pragma unroll
            for (int c = 0; c < 4; c++) sacc[rt][c] = zero4;
        __builtin_amdgcn_s_setprio(1);
#pragma unroll
        for (int c = 0; c < 4; c++) {
            int row = c * 16 + l16;
#pragma unroll
            for (int ks = 0; ks < 2; ks++) {
                short8 kf = *(const short8*)&Ks[cur][row * 64 + (((ks * 4 + quad) ^ (row & 7)) * 8)];
#pragma unroll
                for (int rt = 0; rt < 2; rt++)
                    sacc[rt][c] = __builtin_amdgcn_mfma_f32_16x16x32_bf16(
                        kf, qf[rt][ks], sacc[rt][c], 0, 0, 0);
            }
        }
        __builtin_amdgcn_s_setprio(0);

        // ---- P = exp2(S): packed b64 writes, already B-fragment layout ----
#pragma unroll
        for (int rt = 0; rt < 2; rt++)
#pragma unroll
            for (int c = 0; c < 4; c++) {
                uint2 pv;
                pv.x = pk2(EXP2F(sacc[rt][c][0]), EXP2F(sacc[rt][c][1]));
                pv.y = pk2(EXP2F(sacc[rt][c][2]), EXP2F(sacc[rt][c][3]));
                *(uint2*)&Pl[w][rt * 16 + l16][c * 16 + quad * 4] = pv;
            }

        short8 pf[2][2];
#pragma unroll
        for (int rt = 0; rt < 2; rt++)
#pragma unroll
            for (int ks = 0; ks < 2; ks++)
                pf[rt][ks] = *(const short8*)&Pl[w][rt * 16 + l16][ks * 32 + quad * 8];

        // ---- denominator: lacc[n=q] += sum_s P[q][s] ----
#pragma unroll
        for (int rt = 0; rt < 2; rt++)
#pragma unroll
            for (int ks = 0; ks < 2; ks++)
                lacc[rt] = __builtin_amdgcn_mfma_f32_16x16x32_bf16(
                    ones, pf[rt][ks], lacc[rt], 0, 0, 0);

        // ---- O^T += V^T . P^T : D[m=d][n=q] ----
        __builtin_amdgcn_s_setprio(1);
#pragma unroll
        for (int dt = 0; dt < 4; dt++) {
            int row = dt * 16 + l16;
#pragma unroll
            for (int ks = 0; ks < 2; ks++) {
                short8 vf = *(const short8*)&Vs[cur][row * 64 + (((ks * 4 + quad) ^ (row & 7)) * 8)];
#pragma unroll
                for (int rt = 0; rt < 2; rt++)
                    oacc[rt][dt] = __builtin_amdgcn_mfma_f32_16x16x32_bf16(
                        vf, pf[rt][ks], oacc[rt][dt], 0, 0, 0);
            }
        }
        __builtin_amdgcn_s_setprio(0);

        // retire this tile's ds_reads before next iteration's barrier
        LGKM0();
    }
#undef STAGE_KV

    // ---- normalize (per-lane, no shuffles), bounce through Pl, store ----
#pragma unroll
    for (int rt = 0; rt < 2; rt++) {
        float inv = 1.f / lacc[rt][0];   // all 4 regs identical (A=ones)
#pragma unroll
        for (int dt = 0; dt < 4; dt++) {
            uint2 ov;
            ov.x = pk2(oacc[rt][dt][0] * inv, oacc[rt][dt][1] * inv);
            ov.y = pk2(oacc[rt][dt][2] * inv, oacc[rt][dt][3] * inv);
            *(uint2*)&Pl[w][rt * 16 + l16][dt * 16 + quad * 4] = ov;
        }
    }
    // coalesced 16B stores: 8 lanes cover one 128B row
#pragma unroll
    for (int it = 0; it < 4; it++) {
        int row = it * 8 + (lane >> 3);
        int ch  = lane & 7;
        uint4 val = *(const uint4*)&Pl[w][row][ch * 8];
        *(uint4*)&Ao[((size_t)(q0 + row) * BATCH + b) * DMODEL + hoff + ch * 8] = val;
    }
}

// ---------------------------------------------------------------------------
extern "C" void kernel_launch(void* const* d_in, const int* in_sizes, int n_in,
                              void* d_out, int out_size, void* d_ws, size_t ws_size,
                              hipStream_t stream)
{
    const float* q  = (const float*)d_in[0];
    const float* k  = (const float*)d_in[1];
    const float* v  = (const float*)d_in[2];
    const float* Wq = (const float*)d_in[3];
    const float* bq = (const float*)d_in[4];
    const float* Wk = (const float*)d_in[5];
    const float* bk = (const float*)d_in[6];
    const float* Wv = (const float*)d_in[7];
    const float* bv = (const float*)d_in[8];
    const float* Wo = (const float*)d_in[9];
    const float* bo = (const float*)d_in[10];

    ushort_t* ws = (ushort_t*)d_ws;
    const size_t E = (size_t)M_ROWS * DMODEL;    // 8388608
    const size_t EW = (size_t)DMODEL * DMODEL;   // 1048576
    ushort_t* qb  = ws;            // input q bf16; reused as Vt
    ushort_t* kb  = ws + E;        // input k bf16; reused as Aob
    ushort_t* vb  = ws + 2 * E;
    ushort_t* Qp  = ws + 3 * E;
    ushort_t* Kp  = ws + 4 * E;
    ushort_t* Vp  = ws + 5 * E;
    ushort_t* Wqb = ws + 6 * E;
    ushort_t* Wkb = Wqb + EW;
    ushort_t* Wvb = Wkb + EW;
    ushort_t* Wob = Wvb + EW;
    ushort_t* Vt  = qb;
    ushort_t* Aob = kb;

    const int n4_in = (int)(E / 4);   // 2097152
    const int n4_w  = (int)(EW / 4);  // 262144
    cast_all_bf16<<<dim3(n4_in / 256, 7), 256, 0, stream>>>(
        (const float4*)q, (const float4*)k, (const float4*)v,
        (const float4*)Wq, (const float4*)Wk, (const float4*)Wv, (const float4*)Wo,
        (uint2*)qb, (uint2*)kb, (uint2*)vb,
        (uint2*)Wqb, (uint2*)Wkb, (uint2*)Wvb, (uint2*)Wob,
        n4_in, n4_w);

    // fused QKV projection: 128-tile kernel + XCD swizzle, M = 3*8192.
    gemm_bt_mfma<true><<<dim3(DMODEL / 128, 3 * M_ROWS / 128), 256, 0, stream>>>(
        qb, Wqb, bq, bk, bv, Qp, DMODEL, DMODEL, QSCALE);

    transpose_v<<<dim3(T_SEQ / 64, BATCH * NHEAD), 256, 0, stream>>>(Vp, Vt);

    attn_mfma<<<dim3(8 * 128), 256, 0, stream>>>(Qp, Kp, Vt, Aob);

    // O-proj: 128-tile kernel + XCD swizzle (512 blocks = 2/CU)
    gemm_bt_mfma<false><<<dim3(DMODEL / 128, M_ROWS / 128), 256, 0, stream>>>(
        Aob, Wob, bo, bo, bo, d_out, DMODEL, DMODEL, 1.0f);
}

// Round 8
// 306.388 us; speedup vs baseline: 1.0611x; 1.0002x over previous
//
#include <hip/hip_runtime.h>

// Problem constants (fixed by reference)
#define T_SEQ 1024
#define BATCH 8
#define DMODEL 1024
#define NHEAD 16
#define HDIM 64
#define M_ROWS (T_SEQ * BATCH)   // 8192
// attention scale 0.125 with log2(e) folded in (exp -> exp2)
#define QSCALE (0.125f * 1.44269504088896f)

typedef unsigned short ushort_t;
typedef __attribute__((ext_vector_type(8))) short short8;   // 8 bf16 = 4 VGPRs (MFMA A/B frag)
typedef __attribute__((ext_vector_type(4))) float f32x4;    // MFMA C/D frag

// async global->LDS, 16B per lane; LDS dest = wave-uniform base + lane*16
#define G2L16(g, l) __builtin_amdgcn_global_load_lds(                      \
    (const __attribute__((address_space(1))) void*)(g),                    \
    (__attribute__((address_space(3))) void*)(l), 16, 0, 0)

#define SBAR()   __builtin_amdgcn_s_barrier()
#define LGKM0()  asm volatile("s_waitcnt lgkmcnt(0)" ::: "memory")
#define SCHEDB() __builtin_amdgcn_sched_barrier(0)

// f32 -> bf16 round-to-nearest-even (finite inputs only)
static __device__ __forceinline__ ushort_t f2bf(float f) {
    unsigned int u = __builtin_bit_cast(unsigned int, f);
    u += 0x7FFFu + ((u >> 16) & 1u);
    return (ushort_t)(u >> 16);
}

// pack two f32 -> bf16x2 (lo in [15:0], hi in [31:16]), RNE
#if __has_builtin(__builtin_amdgcn_cvt_pk_bf16_f32)
typedef __attribute__((ext_vector_type(2))) __bf16 bf16x2_t;
static __device__ __forceinline__ unsigned pk2(float lo, float hi) {
    bf16x2_t r = __builtin_amdgcn_cvt_pk_bf16_f32(lo, hi);
    return __builtin_bit_cast(unsigned, r);
}
#else
static __device__ __forceinline__ unsigned pk2(float lo, float hi) {
    return (unsigned)f2bf(lo) | ((unsigned)f2bf(hi) << 16);
}
#endif

// raw v_exp_f32 (2^x)
#if __has_builtin(__builtin_amdgcn_exp2f)
#define EXP2F(x) __builtin_amdgcn_exp2f(x)
#else
#define EXP2F(x) exp2f(x)
#endif

// ---------------------------------------------------------------------------
// Fused f32 -> bf16 cast of all 7 tensors: grid.y selects tensor (uniform
// per block -> scalar pointer selects; proven form).
// ---------------------------------------------------------------------------
__global__ __launch_bounds__(256) void cast_all_bf16(
    const float4* __restrict__ s0, const float4* __restrict__ s1,
    const float4* __restrict__ s2, const float4* __restrict__ s3,
    const float4* __restrict__ s4, const float4* __restrict__ s5,
    const float4* __restrict__ s6,
    uint2* __restrict__ d0, uint2* __restrict__ d1, uint2* __restrict__ d2,
    uint2* __restrict__ d3, uint2* __restrict__ d4, uint2* __restrict__ d5,
    uint2* __restrict__ d6, int n4big, int n4small)
{
    const int y = blockIdx.y;
    const int n4 = (y < 3) ? n4big : n4small;
    const int i = blockIdx.x * 256 + threadIdx.x;
    if (i >= n4) return;
    const float4* s; uint2* d;
    switch (y) {
        case 0: s = s0; d = d0; break;
        case 1: s = s1; d = d1; break;
        case 2: s = s2; d = d2; break;
        case 3: s = s3; d = d3; break;
        case 4: s = s4; d = d4; break;
        case 5: s = s5; d = d5; break;
        default: s = s6; d = d6; break;
    }
    float4 v = s[i];
    uint2 o; o.x = pk2(v.x, v.y); o.y = pk2(v.z, v.w);
    d[i] = o;
}

// ---------------------------------------------------------------------------
// Proven 128x128 4-wave MFMA GEMM + chunked XCD swizzle (FETCH 200.8->44 MB
// verified R6) + __launch_bounds__(256,4) (R7: QKV off top-5).
// Multi-segment: sel = bmg>>6 picks weight/bias (QKV fusion).
// ---------------------------------------------------------------------------
template<bool OUT_BF16>
__global__ __launch_bounds__(256, 4) void gemm_bt_mfma(
    const ushort_t* __restrict__ A, const ushort_t* __restrict__ Wbase,
    const float* __restrict__ bias0, const float* __restrict__ bias1,
    const float* __restrict__ bias2, void* __restrict__ Yv,
    int N, int K, float scale0)
{
    __shared__ ushort_t As[128 * 64];
    __shared__ ushort_t Bs[128 * 64];

    const int tid  = threadIdx.x;
    const int lane = tid & 63;
    const int quad = lane >> 4;
    const int l16  = lane & 15;
    const int w    = tid >> 6;
    const int wm   = w >> 1;
    const int wn   = w & 1;

    // chunked XCD swizzle (bijective: nwg % 8 == 0)
    const int nwg = gridDim.x * gridDim.y;
    const int lin = blockIdx.y * gridDim.x + blockIdx.x;
    const int t   = (lin & 7) * (nwg >> 3) + (lin >> 3);
    const int bn  = t & 7;            // gridDim.x == 8
    const int bmg = t >> 3;

    const int sel = bmg >> 6;                 // 0..2 for QKV, 0 for O-proj
    const ushort_t* Wb = Wbase + (size_t)sel * N * K;
    const float* bias = (sel == 0) ? bias0 : (sel == 1) ? bias1 : bias2;
    const float scale = (sel == 0) ? scale0 : 1.0f;

    const int srow_in = lane >> 3;            // 0..7 within 8-row segment
    const int sch     = lane & 7;             // chunk slot 0..7

    const f32x4 zero4 = {0.f, 0.f, 0.f, 0.f};
    f32x4 acc[4][4];
#pragma unroll
    for (int i = 0; i < 4; i++)
#pragma unroll
        for (int j = 0; j < 4; j++) acc[i][j] = zero4;

    for (int k0 = 0; k0 < K; k0 += 64) {
        __syncthreads();   // previous iter done reading LDS
#pragma unroll
        for (int u = 0; u < 4; u++) {
            int seg = w * 4 + u;              // 0..15, 8 rows each
            int row = seg * 8 + srow_in;      // 0..127
            int chs = sch ^ (row & 7);
            G2L16(&A [(size_t)(bmg * 128 + row) * K + k0 + chs * 8],
                  (char*)As + seg * 1024);
            G2L16(&Wb[(size_t)(bn  * 128 + row) * K + k0 + chs * 8],
                  (char*)Bs + seg * 1024);
        }
        __syncthreads();   // DMA drained

#pragma unroll
        for (int ks = 0; ks < 2; ks++) {
            short8 af[4], bfr[4];
#pragma unroll
            for (int i = 0; i < 4; i++) {
                int row = wm * 64 + i * 16 + l16;
                af[i] = *(const short8*)&As[row * 64 + (((ks * 4 + quad) ^ (row & 7)) * 8)];
            }
#pragma unroll
            for (int j = 0; j < 4; j++) {
                int row = wn * 64 + j * 16 + l16;
                bfr[j] = *(const short8*)&Bs[row * 64 + (((ks * 4 + quad) ^ (row & 7)) * 8)];
            }
#pragma unroll
            for (int i = 0; i < 4; i++)
#pragma unroll
                for (int j = 0; j < 4; j++)
                    acc[i][j] = __builtin_amdgcn_mfma_f32_16x16x32_bf16(
                        af[i], bfr[j], acc[i][j], 0, 0, 0);
        }
    }

    float bj[4];
#pragma unroll
    for (int j = 0; j < 4; j++) bj[j] = bias[bn * 128 + wn * 64 + j * 16 + l16];
#pragma unroll
    for (int i = 0; i < 4; i++) {
#pragma unroll
        for (int r = 0; r < 4; r++) {
            size_t row = (size_t)(bmg * 128 + wm * 64 + i * 16 + quad * 4 + r);
#pragma unroll
            for (int j = 0; j < 4; j++) {
                int col = bn * 128 + wn * 64 + j * 16 + l16;
                float v = (acc[i][j][r] + bj[j]) * scale;
                if (OUT_BF16) ((ushort_t*)Yv)[row * N + col] = f2bf(v);
                else          ((float*)   Yv)[row * N + col] = v;
            }
        }
    }
}

// ---------------------------------------------------------------------------
// Vp (T,B,H,HD) bf16 -> Vt (B,H,HD,T) bf16  (64x64 tiles through LDS)
// ---------------------------------------------------------------------------
__global__ __launch_bounds__(256) void transpose_v(
    const ushort_t* __restrict__ Vp, ushort_t* __restrict__ Vt)
{
    __shared__ ushort_t Ts[64][72];
    const int tid = threadIdx.x;
    const int t0 = blockIdx.x * 64;
    const int bh = blockIdx.y;
    const int b = bh >> 4, h = bh & 15;

#pragma unroll
    for (int u = 0; u < 2; u++) {
        int e = u * 256 + tid;          // 512 chunks of 8 bf16
        int row = e >> 3, ch = (e & 7) * 8;
        uint4 v = *(const uint4*)&Vp[((size_t)(t0 + row) * BATCH + b) * DMODEL + h * 64 + ch];
        *(uint4*)&Ts[row][ch] = v;
    }
    __syncthreads();
#pragma unroll
    for (int u = 0; u < 2; u++) {
        int e = u * 256 + tid;
        int d = e >> 3, tc = (e & 7) * 8;
        uint4 o;
        o.x = (unsigned)Ts[tc + 0][d] | ((unsigned)Ts[tc + 1][d] << 16);
        o.y = (unsigned)Ts[tc + 2][d] | ((unsigned)Ts[tc + 3][d] << 16);
        o.z = (unsigned)Ts[tc + 4][d] | ((unsigned)Ts[tc + 5][d] << 16);
        o.w = (unsigned)Ts[tc + 6][d] | ((unsigned)Ts[tc + 7][d] << 16);
        *(uint4*)&Vt[((size_t)(bh * 64 + d)) * T_SEQ + t0 + tc] = o;
    }
}

// ---------------------------------------------------------------------------
// MFMA flash attention, S^T formulation. R8: LDS cut 50->40 KiB so 4 blocks/CU
// fit (163840/40960 = 4.0): Pl shrunk to [4][16][64] (8 KB) with XOR-swizzled
// 8B slots (slot ^= (row&7)<<1; parity preserved so 16B reads stay
// contiguous). P for both rt packed to bf16 right after QK^T (sacc dies
// early, VGPR peak ~<128); rt processed sequentially through Pl; V fragments
// held in registers across rt so Vs reads don't double. Per-wave DS FIFO
// ordering makes the Pl row reuse safe without barriers (Pl is per-wave).
// ---------------------------------------------------------------------------
__global__ __launch_bounds__(256, 4) void attn_mfma(
    const ushort_t* __restrict__ Qp, const ushort_t* __restrict__ Kp,
    const ushort_t* __restrict__ VtG, ushort_t* __restrict__ Ao)
{
    __shared__ ushort_t Ks[2][64 * 64];  // [s][hd], swizzled, double-buffered
    __shared__ ushort_t Vs[2][64 * 64];  // [hd][s], same structure
    __shared__ ushort_t Pl[4][16][64];   // per-wave P / O-bounce, XOR-swizzled

    const int tid  = threadIdx.x;
    const int lane = tid & 63;
    const int w    = tid >> 6;
    const int quad = lane >> 4;
    const int l16  = lane & 15;
    const int bid  = blockIdx.x;
    const int qb   = bid >> 7;          // 0..7
    const int bh   = bid & 127;
    const int b    = bh >> 4, h = bh & 15;
    const int hoff = h * 64;
    const int q0   = qb * 128 + w * 32;  // this wave's 32 Q rows

    const int srow_in = lane >> 3;       // 0..7 within 8-row segment
    const int sch     = lane & 7;
    const int plswz   = (l16 & 7) << 1;  // per-row slot XOR

    // Q fragments (B-operand; same layout as A), in registers all kernel
    short8 qf[2][2];
#pragma unroll
    for (int rt = 0; rt < 2; rt++)
#pragma unroll
        for (int ks = 0; ks < 2; ks++)
            qf[rt][ks] = *(const short8*)&Qp[((size_t)(q0 + rt * 16 + l16) * BATCH + b) * DMODEL
                                             + hoff + ks * 32 + quad * 8];

    short8 ones;
#pragma unroll
    for (int i = 0; i < 8; i++) ones[i] = (short)0x3F80;   // bf16 1.0

    const f32x4 zero4 = {0.f, 0.f, 0.f, 0.f};
    f32x4 oacc[2][4], lacc[2];
#pragma unroll
    for (int rt = 0; rt < 2; rt++) {
        lacc[rt] = zero4;
#pragma unroll
        for (int c = 0; c < 4; c++) oacc[rt][c] = zero4;
    }

#define STAGE_KV(s0_, buf)                                                       \
    do {                                                                         \
        _Pragma("unroll")                                                        \
        for (int u = 0; u < 2; u++) {                                            \
            int seg = w * 2 + u;                                                 \
            int row = seg * 8 + srow_in;                                         \
            int chs = sch ^ (row & 7);                                           \
            G2L16(&Kp[((size_t)((s0_) + row) * BATCH + b) * DMODEL + hoff + chs * 8], \
                  (char*)&Ks[buf][0] + seg * 1024);                              \
            G2L16(&VtG[((size_t)(bh * 64 + row)) * T_SEQ + (s0_) + chs * 8],     \
                  (char*)&Vs[buf][0] + seg * 1024);                              \
        }                                                                        \
    } while (0)

    STAGE_KV(0, 0);

    for (int it = 0; it < 16; ++it) {
        const int cur = it & 1;

        // own-drain before barrier: tile-it loads (issued >=1 full compute
        // phase ago) landed; after join, all waves' segments are valid.
        asm volatile("s_waitcnt vmcnt(0)" ::: "memory");
        SBAR();
        SCHEDB();
        if (it + 1 < 16) STAGE_KV((it + 1) * 64, cur ^ 1);

        // ---- S^T = K . Q^T : per c-tile D[m=s in c*16..][n=q] ----
        f32x4 sacc[2][4];
#pragma unroll
        for (int rt = 0; rt < 2; rt++)
#pragma unroll
            for (int c = 0; c < 4; c++) sacc[rt][c] = zero4;
        __builtin_amdgcn_s_setprio(1);
#pragma unroll
        for (int c = 0; c < 4; c++) {
            int row = c * 16 + l16;
#pragma unroll
            for (int ks = 0; ks < 2; ks++) {
                short8 kf = *(const short8*)&Ks[cur][row * 64 + (((ks * 4 + quad) ^ (row & 7)) * 8)];
#pragma unroll
                for (int rt = 0; rt < 2; rt++)
                    sacc[rt][c] = __builtin_amdgcn_mfma_f32_16x16x32_bf16(
                        kf, qf[rt][ks], sacc[rt][c], 0, 0, 0);
            }
        }
        __builtin_amdgcn_s_setprio(0);

        // ---- P = exp2(S), packed early for both rt (sacc dies here) ----
        uint2 pk[2][4];
#pragma unroll
        for (int rt = 0; rt < 2; rt++)
#pragma unroll
            for (int c = 0; c < 4; c++) {
                pk[rt][c].x = pk2(EXP2F(sacc[rt][c][0]), EXP2F(sacc[rt][c][1]));
                pk[rt][c].y = pk2(EXP2F(sacc[rt][c][2]), EXP2F(sacc[rt][c][3]));
            }

        // ---- sequential rt through the 16-row Pl (per-wave, DS in-order) ----
        short8 vf[4][2];   // V frags held across rt
#pragma unroll
        for (int rt = 0; rt < 2; rt++) {
#pragma unroll
            for (int c = 0; c < 4; c++) {
                int slot = (c * 4 + quad) ^ plswz;
                *(uint2*)((char*)&Pl[w][l16][0] + slot * 8) = pk[rt][c];
            }
            short8 pf[2];
#pragma unroll
            for (int ks = 0; ks < 2; ks++) {
                int slot = (ks * 8 + quad * 2) ^ plswz;
                pf[ks] = *(const short8*)((const char*)&Pl[w][l16][0] + slot * 8);
            }
            // denominator
#pragma unroll
            for (int ks = 0; ks < 2; ks++)
                lacc[rt] = __builtin_amdgcn_mfma_f32_16x16x32_bf16(
                    ones, pf[ks], lacc[rt], 0, 0, 0);
            // O^T += V^T . P^T
            __builtin_amdgcn_s_setprio(1);
#pragma unroll
            for (int dt = 0; dt < 4; dt++) {
                int row = dt * 16 + l16;
#pragma unroll
                for (int ks = 0; ks < 2; ks++) {
                    if (rt == 0)
                        vf[dt][ks] = *(const short8*)&Vs[cur][row * 64 +
                                     (((ks * 4 + quad) ^ (row & 7)) * 8)];
                    oacc[rt][dt] = __builtin_amdgcn_mfma_f32_16x16x32_bf16(
                        vf[dt][ks], pf[ks], oacc[rt][dt], 0, 0, 0);
                }
            }
            __builtin_amdgcn_s_setprio(0);
        }

        // retire this tile's ds_reads before next iteration's barrier
        LGKM0();
    }
#undef STAGE_KV

    // ---- normalize, bounce through Pl per rt, coalesced 16B stores ----
#pragma unroll
    for (int rt = 0; rt < 2; rt++) {
        float inv = 1.f / lacc[rt][0];   // all 4 regs identical (A=ones)
#pragma unroll
        for (int dt = 0; dt < 4; dt++) {
            uint2 ov;
            ov.x = pk2(oacc[rt][dt][0] * inv, oacc[rt][dt][1] * inv);
            ov.y = pk2(oacc[rt][dt][2] * inv, oacc[rt][dt][3] * inv);
            int slot = (dt * 4 + quad) ^ plswz;
            *(uint2*)((char*)&Pl[w][l16][0] + slot * 8) = ov;
        }
        // 8 lanes cover one 128B row; 16 rows -> 2 iterations
#pragma unroll
        for (int it2 = 0; it2 < 2; it2++) {
            int row = it2 * 8 + (lane >> 3);
            int ch  = lane & 7;
            int slot = (ch * 2) ^ ((row & 7) << 1);
            uint4 val = *(const uint4*)((const char*)&Pl[w][row][0] + slot * 8);
            *(uint4*)&Ao[((size_t)(q0 + rt * 16 + row) * BATCH + b) * DMODEL + hoff + ch * 8] = val;
        }
    }
}

// ---------------------------------------------------------------------------
extern "C" void kernel_launch(void* const* d_in, const int* in_sizes, int n_in,
                              void* d_out, int out_size, void* d_ws, size_t ws_size,
                              hipStream_t stream)
{
    const float* q  = (const float*)d_in[0];
    const float* k  = (const float*)d_in[1];
    const float* v  = (const float*)d_in[2];
    const float* Wq = (const float*)d_in[3];
    const float* bq = (const float*)d_in[4];
    const float* Wk = (const float*)d_in[5];
    const float* bk = (const float*)d_in[6];
    const float* Wv = (const float*)d_in[7];
    const float* bv = (const float*)d_in[8];
    const float* Wo = (const float*)d_in[9];
    const float* bo = (const float*)d_in[10];

    ushort_t* ws = (ushort_t*)d_ws;
    const size_t E = (size_t)M_ROWS * DMODEL;    // 8388608
    const size_t EW = (size_t)DMODEL * DMODEL;   // 1048576
    ushort_t* qb  = ws;            // input q bf16; reused as Vt
    ushort_t* kb  = ws + E;        // input k bf16; reused as Aob
    ushort_t* vb  = ws + 2 * E;
    ushort_t* Qp  = ws + 3 * E;
    ushort_t* Kp  = ws + 4 * E;
    ushort_t* Vp  = ws + 5 * E;
    ushort_t* Wqb = ws + 6 * E;
    ushort_t* Wkb = Wqb + EW;
    ushort_t* Wvb = Wkb + EW;
    ushort_t* Wob = Wvb + EW;
    ushort_t* Vt  = qb;
    ushort_t* Aob = kb;

    const int n4_in = (int)(E / 4);   // 2097152
    const int n4_w  = (int)(EW / 4);  // 262144
    cast_all_bf16<<<dim3(n4_in / 256, 7), 256, 0, stream>>>(
        (const float4*)q, (const float4*)k, (const float4*)v,
        (const float4*)Wq, (const float4*)Wk, (const float4*)Wv, (const float4*)Wo,
        (uint2*)qb, (uint2*)kb, (uint2*)vb,
        (uint2*)Wqb, (uint2*)Wkb, (uint2*)Wvb, (uint2*)Wob,
        n4_in, n4_w);

    // fused QKV projection: 128-tile kernel + XCD swizzle, M = 3*8192.
    gemm_bt_mfma<true><<<dim3(DMODEL / 128, 3 * M_ROWS / 128), 256, 0, stream>>>(
        qb, Wqb, bq, bk, bv, Qp, DMODEL, DMODEL, QSCALE);

    transpose_v<<<dim3(T_SEQ / 64, BATCH * NHEAD), 256, 0, stream>>>(Vp, Vt);

    attn_mfma<<<dim3(8 * 128), 256, 0, stream>>>(Qp, Kp, Vt, Aob);

    // O-proj: 128-tile kernel + XCD swizzle (512 blocks = 2/CU)
    gemm_bt_mfma<false><<<dim3(DMODEL / 128, M_ROWS / 128), 256, 0, stream>>>(
        Aob, Wob, bo, bo, bo, d_out, DMODEL, DMODEL, 1.0f);
}